// Round 1
// baseline (30202.628 us; speedup 1.0000x reference)
//
#include <hip/hip_runtime.h>
#include <hip/hip_cooperative_groups.h>

typedef __attribute__((ext_vector_type(8))) short short8;
typedef __attribute__((ext_vector_type(4))) float floatx4;

#define BQ 16
#define LQ 512
#define DM 1024
#define DPROJ 4384
#define DSSM 2048
#define CONVC 2304
#define NH 32
#define HD 64
#define RAWC 2336   // 2304 rxbc + 32 rdt
#define KD 2048
#define NCOLW 240   // matmul workgroups, 14 cols each -> 3360 = 2304+32+1024
#define WSTR 2056   // LDS weight row stride in shorts (2048 + 8 pad)

__device__ __forceinline__ float siluf(float x) { return x / (1.f + __expf(-x)); }
__device__ __forceinline__ float softplusf(float x) { return (x > 20.f) ? x : log1pf(__expf(x)); }
__device__ __forceinline__ unsigned short f2bf(float f) {
    union { float f; unsigned u; } v; v.f = f;
    unsigned r = v.u + 0x7FFFu + ((v.u >> 16) & 1u);
    return (unsigned short)(r >> 16);
}

// ---------------- fp32 -> bf16 conversion ----------------
__global__ void cvt_bf16_kernel(const float* __restrict__ s, unsigned short* __restrict__ d, int n) {
    int i = blockIdx.x * 256 + threadIdx.x;
    if (i < n) d[i] = f2bf(s[i]);
}

// ---------------- in_proj GEMM: (8192x1024)*(1024x4384) bf16 MFMA ----------------
__global__ __launch_bounds__(256) void gemm_inproj_kernel(const short* __restrict__ A,
                                                          const short* __restrict__ Bw,
                                                          float* __restrict__ C) {
    const int lane = threadIdx.x & 63, wave = threadIdx.x >> 6;
    const int row = lane & 15, q = lane >> 4;
    const long m0 = (long)blockIdx.x * 64 + wave * 16;
    const long n0 = (long)blockIdx.y * 32;
    const short* ap  = A  + (m0 + row) * DM + q * 8;
    const short* bp0 = Bw + (n0 + row) * DM + q * 8;
    const short* bp1 = bp0 + 16 * DM;
    floatx4 acc0 = {0.f,0.f,0.f,0.f}, acc1 = {0.f,0.f,0.f,0.f};
    for (int k = 0; k < DM; k += 32) {
        short8 a  = *(const short8*)(ap + k);
        short8 b0 = *(const short8*)(bp0 + k);
        short8 b1 = *(const short8*)(bp1 + k);
        acc0 = __builtin_amdgcn_mfma_f32_16x16x32_bf16(a, b0, acc0, 0, 0, 0);
        acc1 = __builtin_amdgcn_mfma_f32_16x16x32_bf16(a, b1, acc1, 0, 0, 0);
    }
    float* cp = C + (m0 + q * 4) * DPROJ + n0 + row;
    #pragma unroll
    for (int r = 0; r < 4; ++r) {
        cp[(long)r * DPROJ]      = acc0[r];
        cp[(long)r * DPROJ + 16] = acc1[r];
    }
}

// ---------------- causal depthwise conv (D_CONV=4) ----------------
__global__ void conv_kernel(const float* __restrict__ zx, const float* __restrict__ cw,
                            const float* __restrict__ cb, float* __restrict__ xc) {
    long idx = (long)blockIdx.x * 256 + threadIdx.x;
    const long total = (long)BQ * LQ * CONVC;
    if (idx >= total) return;
    int c = (int)(idx % CONVC);
    long bt = idx / CONVC;
    int t = (int)(bt % LQ);
    long bb = bt / LQ;
    const float* base = zx + (bb * LQ) * DPROJ + DSSM + c;
    float4 wv = *(const float4*)(cw + c * 4);
    float acc = cb[c];
    if (t >= 3) acc += base[(long)(t - 3) * DPROJ] * wv.x;
    if (t >= 2) acc += base[(long)(t - 2) * DPROJ] * wv.y;
    if (t >= 1) acc += base[(long)(t - 1) * DPROJ] * wv.z;
    acc += base[(long)t * DPROJ] * wv.w;
    xc[idx] = acc;
}

// ---------------- zero init of gw + msum ----------------
__global__ void setup_zero_kernel(unsigned short* gw, float* msum) {
    int i = blockIdx.x * 256 + threadIdx.x;
    if (i < BQ * KD) gw[i] = 0;
    if (i < 128) msum[i] = 0.f;
}

// ---------------- cooperative sequential scan ----------------
// grid 256 x block 256. Phase A: wgs 0..239 each own 14 output cols of the fused
// [W_rxbc | W_rdt | W_out] matmul (weights LDS-resident bf16, M=16 batches MFMA).
// Phase B: each wg owns 2 (batch,head) state pairs, state in registers.
__global__ __launch_bounds__(256, 1) void scan_kernel(
    const float* __restrict__ zx,       // [16][512][4384]
    const float* __restrict__ xc,       // [16][512][2304]
    float* __restrict__ raw,            // [16][2336]
    unsigned short* __restrict__ gw,    // [16][2048] bf16 (g * norm_w)
    float* __restrict__ msum,           // [2][64] (stride 64 to split cache lines)
    const float* __restrict__ W_rxbc,   // [2304][2048]
    const float* __restrict__ W_rdt,    // [32][2048]
    const float* __restrict__ W_out,    // [1024][2048]
    const float* __restrict__ dt_bias,  // [32]
    const float* __restrict__ A_log,    // [32]
    const float* __restrict__ D_param,  // [32]
    const float* __restrict__ norm_w,   // [2048]
    float* __restrict__ out)            // [16][512][1024]
{
    cooperative_groups::grid_group grid = cooperative_groups::this_grid();
    const int w = blockIdx.x;
    const int tid = threadIdx.x;
    const int lane = tid & 63;
    const int wave = tid >> 6;

    __shared__ short wtile[14][WSTR];      // 57,568 B
    __shared__ float bc_lds[2][128];       //  1,024 B
    __shared__ float ypart[2][64];         //    512 B
    __shared__ float redu[4][16][16];      //  4,096 B   (total 63,200 B)

    // ---- stage weight slice into LDS (bf16) ----
    if (w < NCOLW) {
        for (int r = 0; r < 14; ++r) {
            int c = w * 14 + r;
            const float* src = (c < 2304) ? (W_rxbc + (long)c * KD)
                             : (c < 2336) ? (W_rdt + (long)(c - 2304) * KD)
                             :              (W_out + (long)(c - 2336) * KD);
            int k0 = tid * 8;
            #pragma unroll
            for (int j = 0; j < 8; ++j) wtile[r][k0 + j] = (short)f2bf(src[k0 + j]);
        }
    }
    __syncthreads();

    // ---- per-wg state assignment ----
    const int pair0 = 2 * w;
    const int b  = pair0 >> 5;                            // batch (both pairs same batch)
    const int h  = (wave < 2) ? (pair0 & 31) : ((pair0 + 1) & 31);
    const int nh = (wave & 1) * 64;                       // n-half of state dim
    float s[64];
    #pragma unroll
    for (int i = 0; i < 64; ++i) s[i] = 0.f;

    const float Aneg = -__expf(A_log[h]);
    const float dtb  = dt_bias[h];
    const float Dp   = D_param[h];
    const float nw   = norm_w[h * 64 + lane];

    const int row = lane & 15;
    const int q   = lane >> 4;
    const int wrow = (row < 14) ? row : 0;                // B-operand LDS row (14 valid cols)

    for (int t = 0; ; ++t) {
        // ======== Phase A: fused matmuls from gw (= yn_{t-1} before rsqrt scale) ========
        if (w < NCOLW) {
            const int kb = wave * 512 + q * 8;
            const short* gp = (const short*)gw + row * KD + kb;
            const short* wp = &wtile[wrow][kb];
            floatx4 acc0 = {0.f,0.f,0.f,0.f};
            floatx4 acc1 = {0.f,0.f,0.f,0.f};
            #pragma unroll
            for (int kk = 0; kk < 512; kk += 64) {
                short8 a0 = *(const short8*)(gp + kk);
                short8 b0 = *(const short8*)(wp + kk);
                short8 a1 = *(const short8*)(gp + kk + 32);
                short8 b1 = *(const short8*)(wp + kk + 32);
                acc0 = __builtin_amdgcn_mfma_f32_16x16x32_bf16(a0, b0, acc0, 0, 0, 0);
                acc1 = __builtin_amdgcn_mfma_f32_16x16x32_bf16(a1, b1, acc1, 0, 0, 0);
            }
            #pragma unroll
            for (int r = 0; r < 4; ++r) redu[wave][q * 4 + r][row] = acc0[r] + acc1[r];
        }
        __syncthreads();
        if (w < NCOLW && wave == 0 && row < 14) {
            const int rp = (t + 1) & 1;   // parity of msum holding step t-1 sums
            const int gc = w * 14 + row;
            #pragma unroll
            for (int r = 0; r < 4; ++r) {
                int orow = q * 4 + r;     // batch index
                float v = redu[0][orow][row] + redu[1][orow][row]
                        + redu[2][orow][row] + redu[3][orow][row];
                float ms = msum[rp * 64 + orow];
                v *= rsqrtf(ms * (1.f / 2048.f) + 1e-5f);
                if (gc < RAWC) { if (t < LQ) raw[orow * RAWC + gc] = v; }
                else           { if (t > 0)  out[((long)orow * LQ + (t - 1)) * DM + gc - RAWC] = v; }
            }
        }
        if (t == LQ) break;
        grid.sync();

        // ======== Phase B: state update, gating, partial RMS ========
        const long btc = (long)(b * LQ + t);
        const float* conv_t = xc + btc * CONVC;
        const float* zx_t   = zx + btc * DPROJ;
        const float* rawb   = raw + b * RAWC;

        if (wave < 2) {                       // B/C for the batch (shared by all heads)
            int n = nh + lane;                // wave0: 0..63, wave1: 64..127
            bc_lds[0][n] = siluf(conv_t[2048 + n] + rawb[2048 + n]);
            bc_lds[1][n] = siluf(conv_t[2176 + n] + rawb[2176 + n]);
        }
        float dtr = siluf(zx_t[4352 + h] + rawb[2304 + h]);
        float dt  = softplusf(dtr + dtb);
        float dA  = __expf(dt * Aneg);
        float xv  = siluf(conv_t[h * 64 + lane] + rawb[h * 64 + lane]);
        __syncthreads();

        float dtx = dt * xv;
        float yac = 0.f;
        const floatx4* Bp = (const floatx4*)&bc_lds[0][nh];
        const floatx4* Cp = (const floatx4*)&bc_lds[1][nh];
        #pragma unroll
        for (int i = 0; i < 16; ++i) {
            floatx4 b4 = Bp[i], c4 = Cp[i];
            s[4*i+0] = s[4*i+0] * dA + dtx * b4.x; yac += s[4*i+0] * c4.x;
            s[4*i+1] = s[4*i+1] * dA + dtx * b4.y; yac += s[4*i+1] * c4.y;
            s[4*i+2] = s[4*i+2] * dA + dtx * b4.z; yac += s[4*i+2] * c4.z;
            s[4*i+3] = s[4*i+3] * dA + dtx * b4.w; yac += s[4*i+3] * c4.w;
        }
        if (wave & 1) ypart[wave >> 1][lane] = yac;
        if (w == 0 && tid < 16) msum[((t + 1) & 1) * 64 + tid] = 0.f;   // reset consumed buffer
        __syncthreads();
        if ((wave & 1) == 0) {
            float y = yac + ypart[wave >> 1][lane] + Dp * xv;
            float g = y * siluf(zx_t[h * 64 + lane]);
            gw[b * KD + h * 64 + lane] = f2bf(g * nw);
            float sq = g * g;
            #pragma unroll
            for (int off = 32; off; off >>= 1) sq += __shfl_xor(sq, off, 64);
            if (lane == 0) atomicAdd(&msum[(t & 1) * 64 + b], sq);
        }
        grid.sync();
    }
}

extern "C" void kernel_launch(void* const* d_in, const int* in_sizes, int n_in,
                              void* d_out, int out_size, void* d_ws, size_t ws_size,
                              hipStream_t stream) {
    const float* u       = (const float*)d_in[0];
    const float* W_in    = (const float*)d_in[1];
    const float* conv_w  = (const float*)d_in[2];
    const float* conv_b  = (const float*)d_in[3];
    const float* W_rxbc  = (const float*)d_in[4];
    const float* W_rdt   = (const float*)d_in[5];
    const float* dt_bias = (const float*)d_in[6];
    const float* A_log   = (const float*)d_in[7];
    const float* D_param = (const float*)d_in[8];
    const float* norm_w  = (const float*)d_in[9];
    const float* W_out   = (const float*)d_in[10];
    float* out = (float*)d_out;

    char* ws = (char*)d_ws;
    size_t off = 0;
    auto alloc = [&](size_t bytes) -> void* {
        void* p = ws + off; off += (bytes + 255) & ~(size_t)255; return p;
    };
    float* zx            = (float*)alloc((size_t)BQ * LQ * DPROJ * 4);   // 143.7 MB
    float* xcv           = (float*)alloc((size_t)BQ * LQ * CONVC * 4);   //  75.5 MB
    unsigned short* u_bf = (unsigned short*)alloc((size_t)BQ * LQ * DM * 2);
    unsigned short* w_bf = (unsigned short*)alloc((size_t)DPROJ * DM * 2);
    unsigned short* gwb  = (unsigned short*)alloc((size_t)BQ * KD * 2);
    float* msum          = (float*)alloc(2 * 64 * 4);
    float* raw           = (float*)alloc((size_t)BQ * RAWC * 4);

    { int n = BQ * LQ * DM; cvt_bf16_kernel<<<(n + 255) / 256, 256, 0, stream>>>(u, u_bf, n); }
    { int n = DPROJ * DM;   cvt_bf16_kernel<<<(n + 255) / 256, 256, 0, stream>>>(W_in, w_bf, n); }
    gemm_inproj_kernel<<<dim3(BQ * LQ / 64, DPROJ / 32), 256, 0, stream>>>(
        (const short*)u_bf, (const short*)w_bf, zx);
    { long n = (long)BQ * LQ * CONVC;
      conv_kernel<<<(int)((n + 255) / 256), 256, 0, stream>>>(zx, conv_w, conv_b, xcv); }
    setup_zero_kernel<<<(BQ * KD + 255) / 256, 256, 0, stream>>>(gwb, msum);

    void* args[] = { &zx, &xcv, &raw, &gwb, &msum, &W_rxbc, &W_rdt, &W_out,
                     &dt_bias, &A_log, &D_param, &norm_w, &out };
    hipLaunchCooperativeKernel((void*)scan_kernel, dim3(256), dim3(256), args, 0, stream);
}

// Round 2
// 10724.400 us; speedup vs baseline: 2.8163x; 2.8163x over previous
//
#include <hip/hip_runtime.h>

typedef __attribute__((ext_vector_type(8))) short short8;
typedef __attribute__((ext_vector_type(4))) float floatx4;

#define BQ 16
#define LQ 512
#define DM 1024
#define DPROJ 4384
#define CONVC 2304
#define RAWC 2336
#define KD 2048
#define NWG 128          // scan workgroups
#define NTHR 512         // threads per scan wg (8 waves)

__device__ __forceinline__ float siluf(float x) { return x / (1.f + __expf(-x)); }
__device__ __forceinline__ float softplusf(float x) { return (x > 20.f) ? x : log1pf(__expf(x)); }
__device__ __forceinline__ unsigned short f2bf(float f) {
    union { float f; unsigned u; } v; v.f = f;
    unsigned r = v.u + 0x7FFFu + ((v.u >> 16) & 1u);
    return (unsigned short)(r >> 16);
}

// ---------------- fp32 -> bf16 conversion ----------------
__global__ void cvt_bf16_kernel(const float* __restrict__ s, unsigned short* __restrict__ d, int n) {
    int i = blockIdx.x * 256 + threadIdx.x;
    if (i < n) d[i] = f2bf(s[i]);
}

// ---------------- pack [W_rxbc|W_rdt|W_out] -> bf16 [3360][2048] ----------------
__global__ void pack_weights_kernel(const float* __restrict__ rxbc, const float* __restrict__ rdt,
                                    const float* __restrict__ wout, unsigned short* __restrict__ wall) {
    long i = (long)blockIdx.x * 256 + threadIdx.x;
    if (i >= 3360L * KD) return;
    int c = (int)(i >> 11), k = (int)(i & 2047);
    const float* src = (c < 2304) ? rxbc + (long)c * KD + k
                     : (c < 2336) ? rdt + (long)(c - 2304) * KD + k
                     :              wout + (long)(c - 2336) * KD + k;
    wall[i] = f2bf(*src);
}

// ---------------- in_proj GEMM: (8192x1024)*(1024x4384) bf16 MFMA ----------------
__global__ __launch_bounds__(256) void gemm_inproj_kernel(const short* __restrict__ A,
                                                          const short* __restrict__ Bw,
                                                          float* __restrict__ C) {
    const int lane = threadIdx.x & 63, wave = threadIdx.x >> 6;
    const int row = lane & 15, q = lane >> 4;
    const long m0 = (long)blockIdx.x * 64 + wave * 16;
    const long n0 = (long)blockIdx.y * 32;
    const short* ap  = A  + (m0 + row) * DM + q * 8;
    const short* bp0 = Bw + (n0 + row) * DM + q * 8;
    const short* bp1 = bp0 + 16 * DM;
    floatx4 acc0 = {0.f,0.f,0.f,0.f}, acc1 = {0.f,0.f,0.f,0.f};
    for (int k = 0; k < DM; k += 32) {
        short8 a  = *(const short8*)(ap + k);
        short8 b0 = *(const short8*)(bp0 + k);
        short8 b1 = *(const short8*)(bp1 + k);
        acc0 = __builtin_amdgcn_mfma_f32_16x16x32_bf16(a, b0, acc0, 0, 0, 0);
        acc1 = __builtin_amdgcn_mfma_f32_16x16x32_bf16(a, b1, acc1, 0, 0, 0);
    }
    float* cp = C + (m0 + q * 4) * DPROJ + n0 + row;
    #pragma unroll
    for (int r = 0; r < 4; ++r) {
        cp[(long)r * DPROJ]      = acc0[r];
        cp[(long)r * DPROJ + 16] = acc1[r];
    }
}

// ---------------- causal depthwise conv (D_CONV=4) ----------------
__global__ void conv_kernel(const float* __restrict__ zx, const float* __restrict__ cw,
                            const float* __restrict__ cb, float* __restrict__ xc) {
    long idx = (long)blockIdx.x * 256 + threadIdx.x;
    const long total = (long)BQ * LQ * CONVC;
    if (idx >= total) return;
    int c = (int)(idx % CONVC);
    long bt = idx / CONVC;
    int t = (int)(bt % LQ);
    long bb = bt / LQ;
    const float* base = zx + (bb * LQ) * DPROJ + 2048 + c;
    float4 wv = *(const float4*)(cw + c * 4);
    float acc = cb[c];
    if (t >= 3) acc += base[(long)(t - 3) * DPROJ] * wv.x;
    if (t >= 2) acc += base[(long)(t - 2) * DPROJ] * wv.y;
    if (t >= 1) acc += base[(long)(t - 1) * DPROJ] * wv.z;
    acc += base[(long)t * DPROJ] * wv.w;
    xc[idx] = acc;
}

// ---------------- zero init of gw + msum + barrier state ----------------
__global__ void setup_zero_kernel(unsigned short* gw, float* msum, unsigned* bar) {
    int i = blockIdx.x * 256 + threadIdx.x;
    if (i < BQ * KD) gw[i] = 0;
    if (i < 128) msum[i] = 0.f;
    if (i < 320) bar[i] = 0u;   // bar[0]=master, bar[32+g*32]=sub-counters
}

// ---------------- lightweight 2-level grid barrier (relaxed agent atomics) ----------------
// k = 1-based barrier round. 128 wgs, 8 sub-counters x 16 arrivals, master counts 8/round.
__device__ __forceinline__ void gbar(unsigned* bar, unsigned k) {
    __syncthreads();   // drains each wave's vmcnt (incl. agent-scope stores) before arrival
    if (threadIdx.x == 0) {
        asm volatile("s_waitcnt vmcnt(0)" ::: "memory");
        unsigned* sub = bar + 32 + (blockIdx.x & 7) * 32;
        unsigned old = __hip_atomic_fetch_add(sub, 1u, __ATOMIC_RELAXED, __HIP_MEMORY_SCOPE_AGENT);
        if (old == k * 16u - 1u)
            __hip_atomic_fetch_add(bar, 1u, __ATOMIC_RELAXED, __HIP_MEMORY_SCOPE_AGENT);
        while (__hip_atomic_load(bar, __ATOMIC_RELAXED, __HIP_MEMORY_SCOPE_AGENT) < k * 8u) {}
    }
    __syncthreads();
}

// ---------------- cooperative sequential scan: 128 wgs x 512 thr ----------------
// Phase A: wgs 0..104, 2 N-tiles (16 cols) each, 4-way K-split per tile (8 waves).
//          Weights bf16 from L2 (normal loads, never invalidated). gw via agent loads.
// Phase B: all 128 wgs: wg w -> batch w>>3, heads (w&7)*4..+3, 8 waves = 4 heads x 2 n-halves,
//          state s[64] per lane in registers.
__global__ __launch_bounds__(NTHR, 2) void scan_kernel(
    const float* __restrict__ zx,       // [16][512][4384]
    const float* __restrict__ xc,       // [16][512][2304]
    float* __restrict__ raw,            // [16][2336]   (agent-scope shared)
    unsigned short* __restrict__ gw,    // [16][2048] bf16 (agent-scope shared)
    float* __restrict__ msum,           // [2][64]      (agent-scope shared)
    unsigned* __restrict__ bar,         // barrier state
    const short* __restrict__ wall,     // [3360][2048] bf16
    const float* __restrict__ dt_bias, const float* __restrict__ A_log,
    const float* __restrict__ D_param, const float* __restrict__ norm_w,
    float* __restrict__ out)            // [16][512][1024]
{
    const int w = blockIdx.x, tid = threadIdx.x;
    const int lane = tid & 63, wv = tid >> 6;

    __shared__ float redu[2][4][16][16];   // 8 KB
    __shared__ float bc_lds[2][128];       // 1 KB
    __shared__ float ypart[4][64];         // 1 KB
    __shared__ float gsum[4];

    // Phase A config
    const bool doA = (w < 105);
    const int colr = lane & 15, q = lane >> 4;
    const int tloc = wv >> 2, kq = wv & 3;
    const int tile = 2 * w + tloc;
    const unsigned long long* gq = (const unsigned long long*)gw;    // [16][512] u64
    const int abase = colr * 512 + kq * 128 + q * 2;
    const short* wp = wall + ((long)(tile * 16 + colr) * KD + kq * 512 + q * 8);

    // Phase B config
    const int b = w >> 3;
    const int h = (w & 7) * 4 + (wv >> 1);
    const int half = wv & 1;
    float s[64];
    #pragma unroll
    for (int i = 0; i < 64; ++i) s[i] = 0.f;
    const float Aneg = -__expf(A_log[h]);
    const float dtb  = dt_bias[h];
    const float Dp   = D_param[h];
    const float nw   = norm_w[h * 64 + lane];

    unsigned target = 0;
    for (int t = 0; ; ++t) {
        // ======== Phase A ========
        if (doA) {
            floatx4 acc = {0.f,0.f,0.f,0.f};
            #pragma unroll 4
            for (int ks = 0; ks < 16; ++ks) {
                unsigned long long a0 = __hip_atomic_load(gq + abase + ks * 8,
                                        __ATOMIC_RELAXED, __HIP_MEMORY_SCOPE_AGENT);
                unsigned long long a1 = __hip_atomic_load(gq + abase + ks * 8 + 1,
                                        __ATOMIC_RELAXED, __HIP_MEMORY_SCOPE_AGENT);
                union { unsigned long long u[2]; short8 s8; } af;
                af.u[0] = a0; af.u[1] = a1;
                short8 bf = *(const short8*)(wp + ks * 32);
                acc = __builtin_amdgcn_mfma_f32_16x16x32_bf16(af.s8, bf, acc, 0, 0, 0);
            }
            #pragma unroll
            for (int r = 0; r < 4; ++r) redu[tloc][kq][q * 4 + r][colr] = acc[r];
        }
        __syncthreads();
        if (doA) {
            int tl = tid >> 8, idx = tid & 255, orow = idx >> 4, col = idx & 15;
            float v = redu[tl][0][orow][col] + redu[tl][1][orow][col]
                    + redu[tl][2][orow][col] + redu[tl][3][orow][col];
            float ms = __hip_atomic_load(msum + ((t + 1) & 1) * 64 + orow,
                                         __ATOMIC_RELAXED, __HIP_MEMORY_SCOPE_AGENT);
            v *= rsqrtf(ms * (1.f / 2048.f) + 1e-5f);
            int gc = (2 * w + tl) * 16 + col;
            if (gc < RAWC) {
                if (t < LQ) __hip_atomic_store(raw + orow * RAWC + gc, v,
                                               __ATOMIC_RELAXED, __HIP_MEMORY_SCOPE_AGENT);
            } else if (t > 0) {
                out[((long)orow * LQ + (t - 1)) * DM + (gc - RAWC)] = v;
            }
        }
        if (t == LQ) break;
        target += NWG; gbar(bar, target / NWG);

        // ======== Phase B ========
        const long btc = (long)b * LQ + t;
        const float* conv_t = xc + btc * CONVC;
        const float* zx_t   = zx + btc * DPROJ;
        float* rawb = raw + b * RAWC;

        if (tid < 256) {
            int which = tid >> 7, n = tid & 127;
            int c = 2048 + which * 128 + n;
            float rv = __hip_atomic_load(rawb + c, __ATOMIC_RELAXED, __HIP_MEMORY_SCOPE_AGENT);
            bc_lds[which][n] = siluf(conv_t[c] + rv);
        }
        float xr   = __hip_atomic_load(rawb + h * 64 + lane, __ATOMIC_RELAXED, __HIP_MEMORY_SCOPE_AGENT);
        float dtrr = __hip_atomic_load(rawb + 2304 + h,      __ATOMIC_RELAXED, __HIP_MEMORY_SCOPE_AGENT);
        float xv = siluf(conv_t[h * 64 + lane] + xr);
        float dt = softplusf(siluf(zx_t[4352 + h] + dtrr) + dtb);
        float dA = __expf(dt * Aneg);
        __syncthreads();

        float dtx = dt * xv, yac = 0.f;
        const floatx4* Bp = (const floatx4*)&bc_lds[0][half * 64];
        const floatx4* Cp = (const floatx4*)&bc_lds[1][half * 64];
        #pragma unroll
        for (int i = 0; i < 16; ++i) {
            floatx4 b4 = Bp[i], c4 = Cp[i];
            s[4*i+0] = s[4*i+0] * dA + dtx * b4.x; yac += s[4*i+0] * c4.x;
            s[4*i+1] = s[4*i+1] * dA + dtx * b4.y; yac += s[4*i+1] * c4.y;
            s[4*i+2] = s[4*i+2] * dA + dtx * b4.z; yac += s[4*i+2] * c4.z;
            s[4*i+3] = s[4*i+3] * dA + dtx * b4.w; yac += s[4*i+3] * c4.w;
        }
        if (half) ypart[wv >> 1][lane] = yac;
        __syncthreads();
        if (!half) {
            float y = yac + ypart[wv >> 1][lane] + Dp * xv;
            float g = y * siluf(zx_t[h * 64 + lane]);
            unsigned gb = (unsigned)f2bf(g * nw);
            unsigned up = __shfl_down(gb, 1);
            if (!(lane & 1))
                __hip_atomic_store((unsigned*)gw + ((b * KD + h * 64 + lane) >> 1),
                                   gb | (up << 16), __ATOMIC_RELAXED, __HIP_MEMORY_SCOPE_AGENT);
            float sq = g * g;
            #pragma unroll
            for (int off = 32; off; off >>= 1) sq += __shfl_xor(sq, off, 64);
            if (lane == 0) gsum[wv >> 1] = sq;
        }
        __syncthreads();
        if (tid == 0) {
            float tot = gsum[0] + gsum[1] + gsum[2] + gsum[3];
            __hip_atomic_fetch_add(msum + (t & 1) * 64 + b, tot,
                                   __ATOMIC_RELAXED, __HIP_MEMORY_SCOPE_AGENT);
        }
        if ((w & 7) == 0 && tid == 64) {
            __hip_atomic_store(msum + ((t + 1) & 1) * 64 + b, 0.f,
                               __ATOMIC_RELAXED, __HIP_MEMORY_SCOPE_AGENT);
        }
        target += NWG; gbar(bar, target / NWG);
    }
}

extern "C" void kernel_launch(void* const* d_in, const int* in_sizes, int n_in,
                              void* d_out, int out_size, void* d_ws, size_t ws_size,
                              hipStream_t stream) {
    const float* u       = (const float*)d_in[0];
    const float* W_in    = (const float*)d_in[1];
    const float* conv_w  = (const float*)d_in[2];
    const float* conv_b  = (const float*)d_in[3];
    const float* W_rxbc  = (const float*)d_in[4];
    const float* W_rdt   = (const float*)d_in[5];
    const float* dt_bias = (const float*)d_in[6];
    const float* A_log   = (const float*)d_in[7];
    const float* D_param = (const float*)d_in[8];
    const float* norm_w  = (const float*)d_in[9];
    const float* W_out   = (const float*)d_in[10];
    float* out = (float*)d_out;

    char* ws = (char*)d_ws;
    size_t off = 0;
    auto alloc = [&](size_t bytes) -> void* {
        void* p = ws + off; off += (bytes + 255) & ~(size_t)255; return p;
    };
    float* zx            = (float*)alloc((size_t)BQ * LQ * DPROJ * 4);
    float* xcv           = (float*)alloc((size_t)BQ * LQ * CONVC * 4);
    unsigned short* u_bf = (unsigned short*)alloc((size_t)BQ * LQ * DM * 2);  // reused as wall
    unsigned short* w_bf = (unsigned short*)alloc((size_t)DPROJ * DM * 2);
    unsigned short* gwb  = (unsigned short*)alloc((size_t)BQ * KD * 2);
    float* msum          = (float*)alloc(2 * 64 * 4);
    float* raw           = (float*)alloc((size_t)BQ * RAWC * 4);
    unsigned* bar        = (unsigned*)alloc(320 * 4);

    { int n = BQ * LQ * DM; cvt_bf16_kernel<<<(n + 255) / 256, 256, 0, stream>>>(u, u_bf, n); }
    { int n = DPROJ * DM;   cvt_bf16_kernel<<<(n + 255) / 256, 256, 0, stream>>>(W_in, w_bf, n); }
    gemm_inproj_kernel<<<dim3(BQ * LQ / 64, DPROJ / 32), 256, 0, stream>>>(
        (const short*)u_bf, (const short*)w_bf, zx);
    // u_bf is dead after the GEMM: reuse its space for the packed scan weights
    unsigned short* wall = u_bf;
    { long n = 3360L * KD;
      pack_weights_kernel<<<(int)((n + 255) / 256), 256, 0, stream>>>(W_rxbc, W_rdt, W_out, wall); }
    { long n = (long)BQ * LQ * CONVC;
      conv_kernel<<<(int)((n + 255) / 256), 256, 0, stream>>>(zx, conv_w, conv_b, xcv); }
    setup_zero_kernel<<<(BQ * KD + 255) / 256, 256, 0, stream>>>(gwb, msum, bar);

    void* args[] = { &zx, &xcv, &raw, &gwb, &msum, &bar, &wall,
                     &dt_bias, &A_log, &D_param, &norm_w, &out };
    hipLaunchCooperativeKernel((void*)scan_kernel, dim3(NWG), dim3(NTHR), args, 0, stream);
}

// Round 3
// 8260.473 us; speedup vs baseline: 3.6563x; 1.2983x over previous
//
#include <hip/hip_runtime.h>

typedef __attribute__((ext_vector_type(8))) short short8;
typedef __attribute__((ext_vector_type(4))) float floatx4;

#define BQ 16
#define LQ 512
#define DM 1024
#define DPROJ 4384
#define CONVC 2304
#define RAWC 2336
#define KD 2048
#define NWG 128          // scan workgroups
#define NTHR 512         // threads per scan wg (8 waves)

__device__ __forceinline__ float siluf(float x) { return x / (1.f + __expf(-x)); }
__device__ __forceinline__ float softplusf(float x) { return (x > 20.f) ? x : log1pf(__expf(x)); }
__device__ __forceinline__ unsigned short f2bf(float f) {
    union { float f; unsigned u; } v; v.f = f;
    unsigned r = v.u + 0x7FFFu + ((v.u >> 16) & 1u);
    return (unsigned short)(r >> 16);
}

// ---------------- fp32 -> bf16 conversion ----------------
__global__ void cvt_bf16_kernel(const float* __restrict__ s, unsigned short* __restrict__ d, int n) {
    int i = blockIdx.x * 256 + threadIdx.x;
    if (i < n) d[i] = f2bf(s[i]);
}

// ---------------- pack [W_rxbc|W_rdt|W_out] -> bf16 [3360][2048] ----------------
__global__ void pack_weights_kernel(const float* __restrict__ rxbc, const float* __restrict__ rdt,
                                    const float* __restrict__ wout, unsigned short* __restrict__ wall) {
    long i = (long)blockIdx.x * 256 + threadIdx.x;
    if (i >= 3360L * KD) return;
    int c = (int)(i >> 11), k = (int)(i & 2047);
    const float* src = (c < 2304) ? rxbc + (long)c * KD + k
                     : (c < 2336) ? rdt + (long)(c - 2304) * KD + k
                     :              wout + (long)(c - 2336) * KD + k;
    wall[i] = f2bf(*src);
}

// ---------------- in_proj GEMM: (8192x1024)*(1024x4384) bf16 MFMA ----------------
__global__ __launch_bounds__(256) void gemm_inproj_kernel(const short* __restrict__ A,
                                                          const short* __restrict__ Bw,
                                                          float* __restrict__ C) {
    const int lane = threadIdx.x & 63, wave = threadIdx.x >> 6;
    const int row = lane & 15, q = lane >> 4;
    const long m0 = (long)blockIdx.x * 64 + wave * 16;
    const long n0 = (long)blockIdx.y * 32;
    const short* ap  = A  + (m0 + row) * DM + q * 8;
    const short* bp0 = Bw + (n0 + row) * DM + q * 8;
    const short* bp1 = bp0 + 16 * DM;
    floatx4 acc0 = {0.f,0.f,0.f,0.f}, acc1 = {0.f,0.f,0.f,0.f};
    for (int k = 0; k < DM; k += 32) {
        short8 a  = *(const short8*)(ap + k);
        short8 b0 = *(const short8*)(bp0 + k);
        short8 b1 = *(const short8*)(bp1 + k);
        acc0 = __builtin_amdgcn_mfma_f32_16x16x32_bf16(a, b0, acc0, 0, 0, 0);
        acc1 = __builtin_amdgcn_mfma_f32_16x16x32_bf16(a, b1, acc1, 0, 0, 0);
    }
    float* cp = C + (m0 + q * 4) * DPROJ + n0 + row;
    #pragma unroll
    for (int r = 0; r < 4; ++r) {
        cp[(long)r * DPROJ]      = acc0[r];
        cp[(long)r * DPROJ + 16] = acc1[r];
    }
}

// ---------------- causal depthwise conv (D_CONV=4) ----------------
__global__ void conv_kernel(const float* __restrict__ zx, const float* __restrict__ cw,
                            const float* __restrict__ cb, float* __restrict__ xc) {
    long idx = (long)blockIdx.x * 256 + threadIdx.x;
    const long total = (long)BQ * LQ * CONVC;
    if (idx >= total) return;
    int c = (int)(idx % CONVC);
    long bt = idx / CONVC;
    int t = (int)(bt % LQ);
    long bb = bt / LQ;
    const float* base = zx + (bb * LQ) * DPROJ + 2048 + c;
    float4 wv = *(const float4*)(cw + c * 4);
    float acc = cb[c];
    if (t >= 3) acc += base[(long)(t - 3) * DPROJ] * wv.x;
    if (t >= 2) acc += base[(long)(t - 2) * DPROJ] * wv.y;
    if (t >= 1) acc += base[(long)(t - 1) * DPROJ] * wv.z;
    acc += base[(long)t * DPROJ] * wv.w;
    xc[idx] = acc;
}

// ---------------- zero init of gw + msum + barrier state ----------------
__global__ void setup_zero_kernel(unsigned short* gw, float* msum, unsigned* bar) {
    int i = blockIdx.x * 256 + threadIdx.x;
    if (i < BQ * KD) gw[i] = 0;
    if (i < 1024) msum[i] = 0.f;    // [2][16][32] padded
    if (i < 320) bar[i] = 0u;       // bar[0]=master, bar[32+g*32]=sub-counters
}

// ---------------- lightweight 2-level grid barrier (relaxed agent atomics) ----------------
__device__ __forceinline__ void gbar(unsigned* bar, unsigned k) {
    __syncthreads();   // each wave drains its own vmcnt before s_barrier
    if (threadIdx.x == 0) {
        asm volatile("s_waitcnt vmcnt(0)" ::: "memory");
        unsigned* sub = bar + 32 + (blockIdx.x & 7) * 32;
        unsigned old = __hip_atomic_fetch_add(sub, 1u, __ATOMIC_RELAXED, __HIP_MEMORY_SCOPE_AGENT);
        if (old == k * 16u - 1u)
            __hip_atomic_fetch_add(bar, 1u, __ATOMIC_RELAXED, __HIP_MEMORY_SCOPE_AGENT);
        while (__hip_atomic_load(bar, __ATOMIC_RELAXED, __HIP_MEMORY_SCOPE_AGENT) < k * 8u) {}
    }
    __syncthreads();
}

// ---------------- cooperative sequential scan: 128 wgs x 512 thr ----------------
// Phase A: wgs 0..104, 2 N-tiles (16 cols), 8-way K-split (1 octant/wave, 8 MFMA/tile),
//          A-fragment preloaded into registers (single exposed L3 latency).
// Phase B: wg w -> batch w>>3, heads (w&7)*4..+3, 8 waves = 4 heads x 2 n-halves,
//          state s[64]/lane in registers; streaming inputs prefetched one step ahead.
__global__ __launch_bounds__(NTHR, 1) void scan_kernel(
    const float* __restrict__ zx,       // [16][512][4384]
    const float* __restrict__ xc,       // [16][512][2304]
    float* __restrict__ raw,            // [16][2336]   (agent-scope shared)
    unsigned short* __restrict__ gw,    // [16][2048] bf16 (agent-scope shared)
    float* __restrict__ msum,           // [2][16][32]  (agent-scope, 1 line/batch)
    unsigned* __restrict__ bar,         // barrier state
    const short* __restrict__ wall,     // [3360][2048] bf16
    const float* __restrict__ dt_bias, const float* __restrict__ A_log,
    const float* __restrict__ D_param, const float* __restrict__ norm_w,
    float* __restrict__ out)            // [16][512][1024]
{
    const int w = blockIdx.x, tid = threadIdx.x;
    const int lane = tid & 63, wv = tid >> 6;

    __shared__ float redu[2][8][16][16];   // 16 KB
    __shared__ float bc_lds[2][128];
    __shared__ float ypart[4][64];
    __shared__ float gsum[4];

    // Phase A config
    const bool doA = (w < 105);
    const int colr = lane & 15, q = lane >> 4;
    const unsigned long long* gq = (const unsigned long long*)gw;  // [16][512] u64
    const int abase = colr * 512 + wv * 64 + q * 2;                // row, K-octant, lane slot
    const short* wp0 = wall + ((long)((2 * w    ) * 16 + colr) * KD + wv * 256 + q * 8);
    const short* wp1 = wall + ((long)((2 * w + 1) * 16 + colr) * KD + wv * 256 + q * 8);
    // reduce-stage mapping: 512 threads -> (tile, batch-row, col)
    const int r_tl = tid >> 8, r_idx = tid & 255, r_orow = r_idx >> 4, r_col = r_idx & 15;

    // Phase B config
    const int b = w >> 3;
    const int h = (w & 7) * 4 + (wv >> 1);
    const int half = wv & 1;
    float s[64];
    #pragma unroll
    for (int i = 0; i < 64; ++i) s[i] = 0.f;
    const float Aneg = -__expf(A_log[h]);
    const float dtb  = dt_bias[h];
    const float Dp   = D_param[h];
    const float nw   = norm_w[h * 64 + lane];
    const int bcw = tid >> 7, bcn = tid & 127;     // bc staging slot (tid<256)

    // prefetch step-0 streaming inputs
    float pf_cx, pf_z, pf_dz, pf_bc = 0.f;
    {
        const long b0 = (long)b * LQ;
        pf_cx = xc[b0 * CONVC + h * 64 + lane];
        pf_z  = zx[b0 * DPROJ + h * 64 + lane];
        pf_dz = zx[b0 * DPROJ + 4352 + h];
        if (tid < 256) pf_bc = xc[b0 * CONVC + 2048 + bcw * 128 + bcn];
    }

    unsigned target = 0;
    for (int t = 0; ; ++t) {
        // ======== Phase A ========
        float msv = 0.f;
        if (doA) {
            // hoisted loads: msum row + full A fragment (independent agent loads)
            msv = __hip_atomic_load(msum + ((t + 1) & 1) * 512 + r_orow * 32,
                                    __ATOMIC_RELAXED, __HIP_MEMORY_SCOPE_AGENT);
            unsigned long long ar[16];
            #pragma unroll
            for (int ks = 0; ks < 8; ++ks) {
                ar[2 * ks]     = __hip_atomic_load(gq + abase + ks * 8,
                                 __ATOMIC_RELAXED, __HIP_MEMORY_SCOPE_AGENT);
                ar[2 * ks + 1] = __hip_atomic_load(gq + abase + ks * 8 + 1,
                                 __ATOMIC_RELAXED, __HIP_MEMORY_SCOPE_AGENT);
            }
            floatx4 acc0 = {0.f,0.f,0.f,0.f}, acc1 = {0.f,0.f,0.f,0.f};
            #pragma unroll
            for (int ks = 0; ks < 8; ++ks) {
                union { unsigned long long u[2]; short8 s8; } af;
                af.u[0] = ar[2 * ks]; af.u[1] = ar[2 * ks + 1];
                short8 b0 = *(const short8*)(wp0 + ks * 32);
                short8 b1 = *(const short8*)(wp1 + ks * 32);
                acc0 = __builtin_amdgcn_mfma_f32_16x16x32_bf16(af.s8, b0, acc0, 0, 0, 0);
                acc1 = __builtin_amdgcn_mfma_f32_16x16x32_bf16(af.s8, b1, acc1, 0, 0, 0);
            }
            #pragma unroll
            for (int r = 0; r < 4; ++r) {
                redu[0][wv][q * 4 + r][colr] = acc0[r];
                redu[1][wv][q * 4 + r][colr] = acc1[r];
            }
        }
        __syncthreads();
        if (doA) {
            float v = 0.f;
            #pragma unroll
            for (int kq = 0; kq < 8; ++kq) v += redu[r_tl][kq][r_orow][r_col];
            v *= rsqrtf(msv * (1.f / 2048.f) + 1e-5f);
            int gc = (2 * w + r_tl) * 16 + r_col;
            if (gc < RAWC) {
                if (t < LQ) __hip_atomic_store(raw + r_orow * RAWC + gc, v,
                                               __ATOMIC_RELAXED, __HIP_MEMORY_SCOPE_AGENT);
            } else if (t > 0) {
                out[((long)r_orow * LQ + (t - 1)) * DM + (gc - RAWC)] = v;
            }
        }
        if (t == LQ) break;
        target += NWG; gbar(bar, target / NWG);

        // ======== Phase B ========
        float* rawb = raw + b * RAWC;
        float bcval = 0.f;
        if (tid < 256) bcval = __hip_atomic_load(rawb + 2048 + bcw * 128 + bcn,
                                                 __ATOMIC_RELAXED, __HIP_MEMORY_SCOPE_AGENT);
        float xr   = __hip_atomic_load(rawb + h * 64 + lane, __ATOMIC_RELAXED, __HIP_MEMORY_SCOPE_AGENT);
        float dtrr = __hip_atomic_load(rawb + 2304 + h,      __ATOMIC_RELAXED, __HIP_MEMORY_SCOPE_AGENT);
        if (tid < 256) bc_lds[bcw][bcn] = siluf(pf_bc + bcval);
        float xv = siluf(pf_cx + xr);
        float dt = softplusf(siluf(pf_dz + dtrr) + dtb);
        float dA = __expf(dt * Aneg);
        float zg = siluf(pf_z);
        __syncthreads();

        float dtx = dt * xv, yac = 0.f;
        const floatx4* Bp = (const floatx4*)&bc_lds[0][half * 64];
        const floatx4* Cp = (const floatx4*)&bc_lds[1][half * 64];
        #pragma unroll
        for (int i = 0; i < 16; ++i) {
            floatx4 b4 = Bp[i], c4 = Cp[i];
            s[4*i+0] = s[4*i+0] * dA + dtx * b4.x; yac += s[4*i+0] * c4.x;
            s[4*i+1] = s[4*i+1] * dA + dtx * b4.y; yac += s[4*i+1] * c4.y;
            s[4*i+2] = s[4*i+2] * dA + dtx * b4.z; yac += s[4*i+2] * c4.z;
            s[4*i+3] = s[4*i+3] * dA + dtx * b4.w; yac += s[4*i+3] * c4.w;
        }
        if (half) ypart[wv >> 1][lane] = yac;
        __syncthreads();
        if (!half) {
            float y = yac + ypart[wv >> 1][lane] + Dp * xv;
            float g = y * zg;
            unsigned gb = (unsigned)f2bf(g * nw);
            unsigned up = __shfl_down(gb, 1);
            if (!(lane & 1))
                __hip_atomic_store((unsigned*)gw + ((b * KD + h * 64 + lane) >> 1),
                                   gb | (up << 16), __ATOMIC_RELAXED, __HIP_MEMORY_SCOPE_AGENT);
            float sq = g * g;
            #pragma unroll
            for (int off = 32; off; off >>= 1) sq += __shfl_xor(sq, off, 64);
            if (lane == 0) gsum[wv >> 1] = sq;
        }
        __syncthreads();
        if (tid == 0) {
            float tot = gsum[0] + gsum[1] + gsum[2] + gsum[3];
            __hip_atomic_fetch_add(msum + (t & 1) * 512 + b * 32, tot,
                                   __ATOMIC_RELAXED, __HIP_MEMORY_SCOPE_AGENT);
        }
        if ((w & 7) == 0 && tid == 64) {
            __hip_atomic_store(msum + ((t + 1) & 1) * 512 + b * 32, 0.f,
                               __ATOMIC_RELAXED, __HIP_MEMORY_SCOPE_AGENT);
        }
        // prefetch next step's streaming inputs (overlaps barrier-2 + Phase A)
        {
            int tp = (t + 1 < LQ) ? t + 1 : LQ - 1;
            const long btp = (long)b * LQ + tp;
            pf_cx = xc[btp * CONVC + h * 64 + lane];
            pf_z  = zx[btp * DPROJ + h * 64 + lane];
            pf_dz = zx[btp * DPROJ + 4352 + h];
            if (tid < 256) pf_bc = xc[btp * CONVC + 2048 + bcw * 128 + bcn];
        }
        target += NWG; gbar(bar, target / NWG);
    }
}

extern "C" void kernel_launch(void* const* d_in, const int* in_sizes, int n_in,
                              void* d_out, int out_size, void* d_ws, size_t ws_size,
                              hipStream_t stream) {
    const float* u       = (const float*)d_in[0];
    const float* W_in    = (const float*)d_in[1];
    const float* conv_w  = (const float*)d_in[2];
    const float* conv_b  = (const float*)d_in[3];
    const float* W_rxbc  = (const float*)d_in[4];
    const float* W_rdt   = (const float*)d_in[5];
    const float* dt_bias = (const float*)d_in[6];
    const float* A_log   = (const float*)d_in[7];
    const float* D_param = (const float*)d_in[8];
    const float* norm_w  = (const float*)d_in[9];
    const float* W_out   = (const float*)d_in[10];
    float* out = (float*)d_out;

    char* ws = (char*)d_ws;
    size_t off = 0;
    auto alloc = [&](size_t bytes) -> void* {
        void* p = ws + off; off += (bytes + 255) & ~(size_t)255; return p;
    };
    float* zx            = (float*)alloc((size_t)BQ * LQ * DPROJ * 4);
    float* xcv           = (float*)alloc((size_t)BQ * LQ * CONVC * 4);
    unsigned short* u_bf = (unsigned short*)alloc((size_t)BQ * LQ * DM * 2);  // reused as wall
    unsigned short* w_bf = (unsigned short*)alloc((size_t)DPROJ * DM * 2);
    unsigned short* gwb  = (unsigned short*)alloc((size_t)BQ * KD * 2);
    float* msum          = (float*)alloc(1024 * 4);
    float* raw           = (float*)alloc((size_t)BQ * RAWC * 4);
    unsigned* bar        = (unsigned*)alloc(320 * 4);

    { int n = BQ * LQ * DM; cvt_bf16_kernel<<<(n + 255) / 256, 256, 0, stream>>>(u, u_bf, n); }
    { int n = DPROJ * DM;   cvt_bf16_kernel<<<(n + 255) / 256, 256, 0, stream>>>(W_in, w_bf, n); }
    gemm_inproj_kernel<<<dim3(BQ * LQ / 64, DPROJ / 32), 256, 0, stream>>>(
        (const short*)u_bf, (const short*)w_bf, zx);
    unsigned short* wall = u_bf;   // dead after GEMM; reuse for packed scan weights
    { long n = 3360L * KD;
      pack_weights_kernel<<<(int)((n + 255) / 256), 256, 0, stream>>>(W_rxbc, W_rdt, W_out, wall); }
    { long n = (long)BQ * LQ * CONVC;
      conv_kernel<<<(int)((n + 255) / 256), 256, 0, stream>>>(zx, conv_w, conv_b, xcv); }
    setup_zero_kernel<<<(BQ * KD + 255) / 256, 256, 0, stream>>>(gwb, msum, bar);

    void* args[] = { &zx, &xcv, &raw, &gwb, &msum, &bar, &wall,
                     &dt_bias, &A_log, &D_param, &norm_w, &out };
    hipLaunchCooperativeKernel((void*)scan_kernel, dim3(NWG), dim3(NTHR), args, 0, stream);
}